// Round 3
// baseline (1315.613 us; speedup 1.0000x reference)
//
#include <hip/hip_runtime.h>
#include <hip/hip_bf16.h>

// ---------------------------------------------------------------------------
// Qwen3.5 GatedDeltaNet forward, MI355X (gfx950)
// B=2 S=2048 HIDDEN=2048 HK=16 HV=32 DK=DV=128 KCONV=4 CHUNK=64
// Pipeline: cast/transpose -> GEMM(qkvz, bf16 out) -> ba+gates ->
//           conv+silu+l2norm (bf16) -> per-chunk (A,T,v_adj,kcd,attn,qg,kdT)
//           -> sequential scan (MFMA) -> gated RMSNorm -> GEMM(out, f32)
// R2->R3: fp32 triangular solve in LDS; negate kcd in fp32 (fixes sign bug).
// Workspace: 370,155,520 B with region aliasing (see kernel_launch).
// ---------------------------------------------------------------------------

typedef short bf16x8 __attribute__((ext_vector_type(8)));
typedef float f32x4  __attribute__((ext_vector_type(4)));

#define MFMA_BF16(a,b,c) __builtin_amdgcn_mfma_f32_16x16x32_bf16((a),(b),(c),0,0,0)
#define GLD16(g,l) __builtin_amdgcn_global_load_lds((const __attribute__((address_space(1))) void*)(g), (__attribute__((address_space(3))) void*)(l), 16, 0, 0)

__device__ __forceinline__ unsigned short f2bf(float x){
  union { float f; unsigned u; } v; v.f = x;
  return (unsigned short)((v.u + 0x7fffu + ((v.u >> 16) & 1u)) >> 16);
}
__device__ __forceinline__ float bf2f(unsigned short h){
  union { unsigned u; float f; } v; v.u = ((unsigned)h) << 16; return v.f;
}
__device__ __forceinline__ unsigned long long pack4bf(float a, float b, float c, float d){
  return (unsigned long long)f2bf(a) | ((unsigned long long)f2bf(b) << 16)
       | ((unsigned long long)f2bf(c) << 32) | ((unsigned long long)f2bf(d) << 48);
}

// ---------------------------------------------------------------------------
__global__ __launch_bounds__(256) void cast_bf16_kernel(
    const float* __restrict__ in, unsigned short* __restrict__ out, int n)
{
  int i = (blockIdx.x * 256 + threadIdx.x) * 4;
  if (i >= n) return;
  float4 v = *(const float4*)(in + i);
  *(unsigned long long*)(out + i) = pack4bf(v.x, v.y, v.z, v.w);
}

// transpose + cast: W[R][C] f32 -> WT[C][R] bf16
__global__ __launch_bounds__(256) void transpose_cast_kernel(
    const float* __restrict__ W, unsigned short* __restrict__ WT, int R, int C)
{
  __shared__ __attribute__((aligned(16))) float tile[32][33];
  int c0 = blockIdx.x * 32, r0 = blockIdx.y * 32;
  int tx = threadIdx.x & 31, ty = threadIdx.x >> 5;
  #pragma unroll
  for (int i = 0; i < 32; i += 8)
    tile[ty + i][tx] = W[(size_t)(r0 + ty + i) * C + c0 + tx];
  __syncthreads();
  #pragma unroll
  for (int i = 0; i < 32; i += 8)
    WT[(size_t)(c0 + ty + i) * R + r0 + tx] = f2bf(tile[tx][ty + i]);
}

// ---------------------------------------------------------------------------
// C[M][N] = A[M][K]bf16 * B[N][K]bf16^T  (128x128 tile, BK=32, XOR-swizzled LDS)
template<bool BF16OUT>
__global__ __launch_bounds__(256) void gemm_bt(
    const unsigned short* __restrict__ A,
    const unsigned short* __restrict__ B,
    void* __restrict__ Cv, int M, int N, int K)
{
  __shared__ __attribute__((aligned(16))) unsigned short Abuf[128 * 32];
  __shared__ __attribute__((aligned(16))) unsigned short Bbuf[128 * 32];
  const int tid  = threadIdx.x;
  const int wave = tid >> 6, lane = tid & 63;
  const int quad = lane >> 4, l16 = lane & 15;
  const int m0 = blockIdx.x * 128, n0 = blockIdx.y * 128;
  const int wm = (wave & 1) * 64, wn = (wave >> 1) * 64;

  f32x4 acc[4][4];
  #pragma unroll
  for (int a = 0; a < 4; ++a)
    #pragma unroll
    for (int b = 0; b < 4; ++b)
      #pragma unroll
      for (int r = 0; r < 4; ++r) acc[a][b][r] = 0.f;

  const int nkt = K >> 5;
  for (int kt = 0; kt < nkt; ++kt) {
    const int k0 = kt << 5;
    __syncthreads();
    #pragma unroll
    for (int c = 0; c < 2; ++c) {
      int p   = (wave * 2 + c) * 64 + lane;
      int m   = p >> 2;
      int gch = (p & 3) ^ ((m >> 2) & 3);
      GLD16(A + (size_t)(m0 + m) * K + k0 + gch * 8, Abuf + (wave * 2 + c) * 512);
      GLD16(B + (size_t)(n0 + m) * K + k0 + gch * 8, Bbuf + (wave * 2 + c) * 512);
    }
    __syncthreads();
    bf16x8 af[4], bfv[4];
    #pragma unroll
    for (int mt = 0; mt < 4; ++mt) {
      int m = wm + mt * 16 + l16;
      af[mt] = *(const bf16x8*)(Abuf + (m * 4 + (quad ^ ((m >> 2) & 3))) * 8);
    }
    #pragma unroll
    for (int nt = 0; nt < 4; ++nt) {
      int n = wn + nt * 16 + l16;
      bfv[nt] = *(const bf16x8*)(Bbuf + (n * 4 + (quad ^ ((n >> 2) & 3))) * 8);
    }
    #pragma unroll
    for (int mt = 0; mt < 4; ++mt)
      #pragma unroll
      for (int nt = 0; nt < 4; ++nt)
        acc[mt][nt] = MFMA_BF16(af[mt], bfv[nt], acc[mt][nt]);
  }
  #pragma unroll
  for (int mt = 0; mt < 4; ++mt) {
    #pragma unroll
    for (int nt = 0; nt < 4; ++nt) {
      int row = m0 + wm + mt * 16 + quad * 4;
      int col = n0 + wn + nt * 16 + l16;
      #pragma unroll
      for (int r = 0; r < 4; ++r) {
        if (BF16OUT)
          ((unsigned short*)Cv)[(size_t)(row + r) * N + col] = f2bf(acc[mt][nt][r]);
        else
          ((float*)Cv)[(size_t)(row + r) * N + col] = acc[mt][nt][r];
      }
    }
  }
}

// ---------------------------------------------------------------------------
// ba = H @ W_ba (fp32), beta = sigmoid(b), g = -exp(A_log)*softplus(a+dt_bias)
__global__ __launch_bounds__(256) void ba_kernel(
    const float* __restrict__ H, const float* __restrict__ Wba,
    const float* __restrict__ dtb, const float* __restrict__ Alog,
    float* __restrict__ bbuf, float* __restrict__ gbuf)
{
  int t = threadIdx.x;
  int col = t & 63, wv = t >> 6;
  int m0 = blockIdx.x * 16 + wv * 4;
  const float* h0 = H + (size_t)m0 * 2048;
  float a0 = 0.f, a1 = 0.f, a2 = 0.f, a3 = 0.f;
  for (int k = 0; k < 2048; ++k) {
    float w = Wba[k * 64 + col];
    a0 += h0[k]        * w;
    a1 += h0[2048 + k] * w;
    a2 += h0[4096 + k] * w;
    a3 += h0[6144 + k] * w;
  }
  float accv[4] = {a0, a1, a2, a3};
  #pragma unroll
  for (int r = 0; r < 4; ++r) {
    int m = m0 + r;
    int b = m >> 11, s = m & 2047;
    float acc = accv[r];
    if (col < 32) {
      bbuf[((size_t)(b * 32 + col)) * 2048 + s] = 1.f / (1.f + __expf(-acc));
    } else {
      int hh = col - 32;
      float x  = acc + dtb[hh];
      float sp = (x > 20.f) ? x : log1pf(__expf(x));
      gbuf[((size_t)(b * 32 + hh)) * 2048 + s] = -__expf(Alog[hh]) * sp;
    }
  }
}

// ---------------------------------------------------------------------------
// causal depthwise conv (K=4) + silu + (q,k) l2-norm (q also * DK^-0.5)
__global__ __launch_bounds__(128) void conv_kernel(
    const unsigned short* __restrict__ qkvz, const float* __restrict__ cw,
    unsigned short* __restrict__ qn, unsigned short* __restrict__ kn,
    unsigned short* __restrict__ vb)
{
  int s_base = blockIdx.x * 4;
  int head   = blockIdx.y;
  int d      = threadIdx.x;
  int col    = head * 128 + d;
  int s_loc  = s_base & 2047;

  float vin[7];
  #pragma unroll
  for (int t = 0; t < 7; ++t) {
    int sp = s_loc + t - 3;
    vin[t] = (sp >= 0) ? bf2f(qkvz[(size_t)(s_base + t - 3) * 12288 + col]) : 0.f;
  }
  float w0 = cw[col*4], w1 = cw[col*4+1], w2 = cw[col*4+2], w3 = cw[col*4+3];
  float y[4];
  #pragma unroll
  for (int u = 0; u < 4; ++u) {
    float acc = vin[u]*w0 + vin[u+1]*w1 + vin[u+2]*w2 + vin[u+3]*w3;
    y[u] = acc / (1.f + __expf(-acc));
  }
  if (head < 32) {
    __shared__ float red[2][4];
    int wv = threadIdx.x >> 6;
    #pragma unroll
    for (int u = 0; u < 4; ++u) {
      float ss = y[u] * y[u];
      #pragma unroll
      for (int off = 32; off; off >>= 1) ss += __shfl_down(ss, off);
      if ((threadIdx.x & 63) == 0) red[wv][u] = ss;
    }
    __syncthreads();
    #pragma unroll
    for (int u = 0; u < 4; ++u) {
      float r = rsqrtf(red[0][u] + red[1][u] + 1e-6f);
      if (head < 16)
        qn[((size_t)(s_base + u) * 16 + head) * 128 + d] = f2bf(y[u] * r * 0.08838834764831845f);
      else
        kn[((size_t)(s_base + u) * 16 + (head - 16)) * 128 + d] = f2bf(y[u] * r);
    }
  } else {
    #pragma unroll
    for (int u = 0; u < 4; ++u)
      vb[((size_t)(s_base + u) * 32 + (head - 32)) * 128 + d] = f2bf(y[u]);
  }
}

// ---------------------------------------------------------------------------
// per-chunk: A=(beta k)k^T * decay (strict lower), attn=q k^T * decay,
// fp32 forward-substitution solve on [v*beta | k*beta*e^gc], outputs packed.
__global__ __launch_bounds__(256) void chunk_kernel(
    const unsigned short* __restrict__ qnb, const unsigned short* __restrict__ knb,
    const unsigned short* __restrict__ vbb,
    const float* __restrict__ gbuf, const float* __restrict__ bbuf,
    unsigned short* __restrict__ attnb, unsigned short* __restrict__ vadjb,
    unsigned short* __restrict__ kcdn, unsigned short* __restrict__ qgb,
    unsigned short* __restrict__ kdT, float* __restrict__ egl)
{
  int cid = blockIdx.x;
  int n = cid & 31, h = (cid >> 5) & 31, b = cid >> 10;
  int h2 = h >> 1, s0 = n * 64;
  int gs0 = b * 2048 + s0;
  int tid = threadIdx.x, wave = tid >> 6, lane = tid & 63, quad = lane >> 4, l16 = lane & 15;

  __shared__ __attribute__((aligned(16))) unsigned short kS[64 * 136]; // bf16 k tile
  __shared__ __attribute__((aligned(16))) float As[64 * 68];           // fp32 A
  __shared__ __attribute__((aligned(16))) float Xs[64 * 260];          // fp32 [v*b | k*b*e^gc]
  __shared__ float gcS[64], betaS[64];

  if (tid < 64) {
    gcS[tid]   = gbuf[((size_t)(b * 32 + h)) * 2048 + s0 + tid];
    betaS[tid] = bbuf[((size_t)(b * 32 + h)) * 2048 + s0 + tid];
  }
  __syncthreads();
  if (tid == 0) {                 // inclusive cumsum of g
    float run = 0.f;
    for (int i = 0; i < 64; ++i) { run += gcS[i]; gcS[i] = run; }
  }
  {                               // stage k tile -> LDS (bf16 copy)
    int i = tid >> 2, seg = tid & 3;
    const bf16x8* kp = (const bf16x8*)(knb + ((size_t)(gs0 + i) * 16 + h2) * 128 + seg * 32);
    bf16x8* kd_ = (bf16x8*)(kS + i * 136 + seg * 32);
    #pragma unroll
    for (int u = 0; u < 4; ++u) kd_[u] = kp[u];
  }
  __syncthreads();

  // phase 1: A and attn via MFMA (wave w owns i-tile w)
  {
    int arow = wave * 16 + l16;
    float bscale = betaS[arow];
    const unsigned short* qpg = qnb + ((size_t)(gs0 + arow) * 16 + h2) * 128;
    bf16x8 kbf[4], qf[4];
    #pragma unroll
    for (int ks = 0; ks < 4; ++ks) {
      bf16x8 kfr = *(const bf16x8*)(kS + arow * 136 + ks * 32 + quad * 8);
      bf16x8 t;
      #pragma unroll
      for (int e = 0; e < 8; ++e)
        t[e] = (short)f2bf(bf2f((unsigned short)kfr[e]) * bscale);
      kbf[ks] = t;
      qf[ks] = *(const bf16x8*)(qpg + ks * 32 + quad * 8);
    }
    #pragma unroll
    for (int jt = 0; jt < 4; ++jt) {
      f32x4 accA, accQ;
      #pragma unroll
      for (int r = 0; r < 4; ++r) { accA[r] = 0.f; accQ[r] = 0.f; }
      #pragma unroll
      for (int ks = 0; ks < 4; ++ks) {
        bf16x8 bfr = *(const bf16x8*)(kS + (jt * 16 + l16) * 136 + ks * 32 + quad * 8);
        accA = MFMA_BF16(kbf[ks], bfr, accA);
        accQ = MFMA_BF16(qf[ks],  bfr, accQ);
      }
      #pragma unroll
      for (int r = 0; r < 4; ++r) {
        int i = wave * 16 + quad * 4 + r;
        int j = jt * 16 + l16;
        float e = __expf(gcS[i] - gcS[j]);
        As[i * 68 + j] = (j < i) ? (accA[r] * e) : 0.f;
        attnb[(size_t)cid * 4096 + i * 64 + j] = (j <= i) ? f2bf(accQ[r] * e) : (unsigned short)0;
      }
    }
  }
  __syncthreads();

  // phase 2: RHS init X = [v*beta | k*beta*e^gc]  (fp32)
  {
    int i = tid >> 2, seg = tid & 3;
    float bta = betaS[i];
    float egc = __expf(gcS[i]);
    const unsigned short* vp = vbb + ((size_t)(gs0 + i) * 32 + h) * 128 + seg * 32;
    #pragma unroll
    for (int u = 0; u < 32; ++u)
      Xs[i * 260 + seg * 32 + u] = bf2f(vp[u]) * bta;
    const unsigned short* kp = kS + i * 136 + seg * 32;
    float sc = bta * egc;
    #pragma unroll
    for (int u = 0; u < 32; ++u)
      Xs[i * 260 + 128 + seg * 32 + u] = bf2f(kp[u]) * sc;
  }
  __syncthreads();

  // phase 3: fp32 forward substitution (I+A)X = RHS, 256 columns in parallel
  {
    int c = tid;
    for (int i = 1; i < 64; ++i) {
      float s = 0.f;
      const float* ar = As + i * 68;
      for (int j = 0; j < i; ++j)
        s += ar[j] * Xs[j * 260 + c];
      Xs[i * 260 + c] -= s;
      __syncthreads();
    }
  }

  // phase 4: pack outputs (all negation/scaling in fp32)
  {
    int i = tid >> 2, seg = tid & 3;
    float egli = __expf(gcS[63] - gcS[i]);
    float eqi  = __expf(gcS[i]);
    size_t base128 = (size_t)cid * 8192 + i * 128 + seg * 32;
    const float* xv = Xs + i * 260 + seg * 32;
    const float* xk = Xs + i * 260 + 128 + seg * 32;
    #pragma unroll
    for (int u = 0; u < 32; u += 4) {
      *(unsigned long long*)(vadjb + base128 + u) =
          pack4bf(xv[u], xv[u+1], xv[u+2], xv[u+3]);
      *(unsigned long long*)(kcdn + base128 + u) =
          pack4bf(-xk[u], -xk[u+1], -xk[u+2], -xk[u+3]);
    }
    const unsigned short* qp = qnb + ((size_t)(gs0 + i) * 16 + h2) * 128 + seg * 32;
    #pragma unroll
    for (int u = 0; u < 32; u += 4) {
      *(unsigned long long*)(qgb + base128 + u) =
          pack4bf(bf2f(qp[u]) * eqi, bf2f(qp[u+1]) * eqi, bf2f(qp[u+2]) * eqi, bf2f(qp[u+3]) * eqi);
    }
    const unsigned short* kp = kS + i * 136 + seg * 32;
    unsigned short* kdo = kdT + (size_t)cid * 8192;
    #pragma unroll
    for (int u = 0; u < 32; ++u) {
      int d = seg * 32 + u;
      kdo[(size_t)d * 64 + i] = f2bf(bf2f(kp[u]) * egli);
    }
    if (tid == 0) egl[cid] = __expf(gcS[63]);
  }
}

// ---------------------------------------------------------------------------
// sequential scan over 32 chunks. grid (64 bh, 4 dv-slices of 32). MFMA throughout.
__global__ __launch_bounds__(256) void scan_kernel(
    const unsigned short* __restrict__ qgb, const unsigned short* __restrict__ kcdn,
    const unsigned short* __restrict__ attnb, const unsigned short* __restrict__ kdT,
    const unsigned short* __restrict__ vadjb, const float* __restrict__ egl,
    unsigned short* __restrict__ obuf)
{
  int bh = blockIdx.x, dv0 = blockIdx.y * 32;
  int tid = threadIdx.x, w = tid >> 6, lane = tid & 63, quad = lane >> 4, l16 = lane & 15;
  __shared__ __attribute__((aligned(16))) unsigned short stT[32 * 136];
  __shared__ __attribute__((aligned(16))) unsigned short vnT[32 * 72];

  for (int idx = tid; idx < 32 * 136; idx += 256) stT[idx] = 0;
  f32x4 st[2][2];
  #pragma unroll
  for (int a = 0; a < 2; ++a)
    #pragma unroll
    for (int bq = 0; bq < 2; ++bq)
      #pragma unroll
      for (int r = 0; r < 4; ++r) st[a][bq][r] = 0.f;
  __syncthreads();

  for (int n = 0; n < 32; ++n) {
    size_t cid = (size_t)bh * 32 + n;
    const unsigned short* qgc = qgb  + cid * 8192;
    const unsigned short* kcc = kcdn + cid * 8192;
    const unsigned short* atc = attnb + cid * 4096;
    const unsigned short* kdc = kdT  + cid * 8192;
    const unsigned short* vac = vadjb + cid * 8192;
    float a = egl[cid];

    bf16x8 sf[2][4];
    #pragma unroll
    for (int ni = 0; ni < 2; ++ni)
      #pragma unroll
      for (int ks = 0; ks < 4; ++ks)
        sf[ni][ks] = *(const bf16x8*)(stT + (ni * 16 + l16) * 136 + ks * 32 + quad * 8);

    // v_new = v_adj - kcd @ state  (kcd stored negated in fp32 pack)
    f32x4 vacc[2];
    #pragma unroll
    for (int ni = 0; ni < 2; ++ni)
      #pragma unroll
      for (int r = 0; r < 4; ++r)
        vacc[ni][r] = bf2f(vac[(size_t)(w * 16 + quad * 4 + r) * 128 + dv0 + ni * 16 + l16]);
    bf16x8 kf[4];
    #pragma unroll
    for (int ks = 0; ks < 4; ++ks)
      kf[ks] = *(const bf16x8*)(kcc + (size_t)(w * 16 + l16) * 128 + ks * 32 + quad * 8);
    #pragma unroll
    for (int ni = 0; ni < 2; ++ni)
      #pragma unroll
      for (int ks = 0; ks < 4; ++ks)
        vacc[ni] = MFMA_BF16(kf[ks], sf[ni][ks], vacc[ni]);

    // o (part1) = (q e^gc) @ state
    f32x4 oacc[2];
    #pragma unroll
    for (int ni = 0; ni < 2; ++ni)
      #pragma unroll
      for (int r = 0; r < 4; ++r) oacc[ni][r] = 0.f;
    bf16x8 qf[4];
    #pragma unroll
    for (int ks = 0; ks < 4; ++ks)
      qf[ks] = *(const bf16x8*)(qgc + (size_t)(w * 16 + l16) * 128 + ks * 32 + quad * 8);
    #pragma unroll
    for (int ni = 0; ni < 2; ++ni)
      #pragma unroll
      for (int ks = 0; ks < 4; ++ks)
        oacc[ni] = MFMA_BF16(qf[ks], sf[ni][ks], oacc[ni]);

    // publish v_new^T
    #pragma unroll
    for (int ni = 0; ni < 2; ++ni)
      #pragma unroll
      for (int r = 0; r < 4; ++r)
        vnT[(ni * 16 + l16) * 72 + w * 16 + quad * 4 + r] = f2bf(vacc[ni][r]);
    __syncthreads();

    // o (part2) += attn @ v_new ; store o (bf16)
    bf16x8 af2[2], vf[2][2];
    #pragma unroll
    for (int k2 = 0; k2 < 2; ++k2)
      af2[k2] = *(const bf16x8*)(atc + (size_t)(w * 16 + l16) * 64 + k2 * 32 + quad * 8);
    #pragma unroll
    for (int ni = 0; ni < 2; ++ni)
      #pragma unroll
      for (int k2 = 0; k2 < 2; ++k2)
        vf[ni][k2] = *(const bf16x8*)(vnT + (ni * 16 + l16) * 72 + k2 * 32 + quad * 8);
    #pragma unroll
    for (int ni = 0; ni < 2; ++ni)
      #pragma unroll
      for (int k2 = 0; k2 < 2; ++k2)
        oacc[ni] = MFMA_BF16(af2[k2], vf[ni][k2], oacc[ni]);
    unsigned short* op = obuf + ((size_t)bh * 2048 + n * 64) * 128;
    #pragma unroll
    for (int ni = 0; ni < 2; ++ni)
      #pragma unroll
      for (int r = 0; r < 4; ++r)
        op[(size_t)(w * 16 + quad * 4 + r) * 128 + dv0 + ni * 16 + l16] = f2bf(oacc[ni][r]);

    // state = a*state + kdT @ v_new  (fp32 master in regs)
    #pragma unroll
    for (int mi = 0; mi < 2; ++mi) {
      int mg = (w * 2 + mi) * 16;
      bf16x8 kdf[2];
      #pragma unroll
      for (int k2 = 0; k2 < 2; ++k2)
        kdf[k2] = *(const bf16x8*)(kdc + (size_t)(mg + l16) * 64 + k2 * 32 + quad * 8);
      #pragma unroll
      for (int ni = 0; ni < 2; ++ni) {
        f32x4 acc_;
        #pragma unroll
        for (int r = 0; r < 4; ++r) acc_[r] = a * st[mi][ni][r];
        #pragma unroll
        for (int k2 = 0; k2 < 2; ++k2)
          acc_ = MFMA_BF16(kdf[k2], vf[ni][k2], acc_);
        st[mi][ni] = acc_;
      }
    }
    // publish state^T bf16 for next chunk
    #pragma unroll
    for (int mi = 0; mi < 2; ++mi)
      #pragma unroll
      for (int ni = 0; ni < 2; ++ni)
        #pragma unroll
        for (int r = 0; r < 4; ++r)
          stT[(ni * 16 + l16) * 136 + (w * 2 + mi) * 16 + quad * 4 + r] = f2bf(st[mi][ni][r]);
    __syncthreads();
  }
}

// ---------------------------------------------------------------------------
// gated RMSNorm: rmsnorm(o)*w*silu(z) -> gated bf16 [B*S][HV*128]
__global__ __launch_bounds__(64) void gate_kernel(
    const unsigned short* __restrict__ obuf, const unsigned short* __restrict__ qkvz,
    const float* __restrict__ nw, unsigned short* __restrict__ gated)
{
  int id = blockIdx.x;            // (b*2048+s)*32 + h
  int h = id & 31, bs = id >> 5;
  int b = bs >> 11, s = bs & 2047;
  int lane = threadIdx.x;
  const unsigned short* op = obuf + (((size_t)(b * 32 + h)) * 2048 + s) * 128;
  const unsigned short* zp = qkvz + (size_t)bs * 12288 + 8192 + h * 128;
  float x0 = bf2f(op[lane]), x1 = bf2f(op[lane + 64]);
  float ss = x0 * x0 + x1 * x1;
  #pragma unroll
  for (int off = 32; off; off >>= 1) ss += __shfl_down(ss, off);
  ss = __shfl(ss, 0);
  float r = rsqrtf(ss * (1.f / 128.f) + 1e-6f);
  float z0 = bf2f(zp[lane]), z1 = bf2f(zp[lane + 64]);
  float g0 = z0 / (1.f + __expf(-z0)), g1 = z1 / (1.f + __expf(-z1));
  unsigned short* gp = gated + (size_t)bs * 4096 + h * 128;
  gp[lane]      = f2bf(x0 * r * nw[lane]      * g0);
  gp[lane + 64] = f2bf(x1 * r * nw[lane + 64] * g1);
}

// ---------------------------------------------------------------------------
extern "C" void kernel_launch(void* const* d_in, const int* in_sizes, int n_in,
                              void* d_out, int out_size, void* d_ws, size_t ws_size,
                              hipStream_t stream)
{
  const float* H     = (const float*)d_in[0];
  const float* Wqkvz = (const float*)d_in[1];
  const float* Wba   = (const float*)d_in[2];
  const float* cw    = (const float*)d_in[3];
  const float* dtb   = (const float*)d_in[4];
  const float* Alog  = (const float*)d_in[5];
  const float* nw    = (const float*)d_in[6];
  const float* Wout  = (const float*)d_in[7];
  float* out = (float*)d_out;

  // ---- workspace arena (370,155,520 B) with aliasing ----
  const size_t U1 = 0;                      //  67,108,864: Hbf+WqT -> qn+kn+vb
  const size_t U2 = U1 + 67108864;          // 100,663,296: qkvz bf16 (z until gate)
  const size_t U3 = U2 + 100663296;         //  16,777,216: WoT
  const size_t U4 = U3 + 16777216;          //   1,048,576: bbuf+gbuf
  const size_t U5 = U4 + 1048576;           // 151,003,136: chunk outputs -> gated
  const size_t U6 = U5 + 151003136;         //  33,554,432: obuf bf16
  const size_t NEED = U6 + 33554432;        // 370,155,520
  if (ws_size < NEED) return;               // graceful fail (diagnostic)

  char* base = (char*)d_ws;
  unsigned short* Hbf   = (unsigned short*)(base + U1);
  unsigned short* WqT   = (unsigned short*)(base + U1 + 16777216);
  unsigned short* qnb   = (unsigned short*)(base + U1);              // after GEMM1
  unsigned short* knb   = (unsigned short*)(base + U1 + 16777216);   // after GEMM1
  unsigned short* vbb   = (unsigned short*)(base + U1 + 33554432);   // after GEMM1
  unsigned short* qkvzb = (unsigned short*)(base + U2);
  unsigned short* WoT   = (unsigned short*)(base + U3);
  float*          bbuf  = (float*)(base + U4);
  float*          gbuf  = (float*)(base + U4 + 524288);
  unsigned short* attnb = (unsigned short*)(base + U5);
  unsigned short* vadjb = (unsigned short*)(base + U5 + 16777216);
  unsigned short* kcdn  = (unsigned short*)(base + U5 + 50331648);
  unsigned short* qgb   = (unsigned short*)(base + U5 + 83886080);
  unsigned short* kdTb  = (unsigned short*)(base + U5 + 117440512);
  float*          egl   = (float*)(base + U5 + 150994944);
  unsigned short* gated = (unsigned short*)(base + U5);              // after scan
  unsigned short* obuf  = (unsigned short*)(base + U6);

  cast_bf16_kernel<<<8192, 256, 0, stream>>>(H, Hbf, 4096 * 2048);
  transpose_cast_kernel<<<dim3(12288 / 32, 2048 / 32), 256, 0, stream>>>(Wqkvz, WqT, 2048, 12288);
  transpose_cast_kernel<<<dim3(2048 / 32, 4096 / 32), 256, 0, stream>>>(Wout, WoT, 4096, 2048);
  gemm_bt<true><<<dim3(32, 96), 256, 0, stream>>>(Hbf, WqT, qkvzb, 4096, 12288, 2048);
  ba_kernel<<<256, 256, 0, stream>>>(H, Wba, dtb, Alog, bbuf, gbuf);
  conv_kernel<<<dim3(1024, 64), 128, 0, stream>>>(qkvzb, cw, qnb, knb, vbb);
  chunk_kernel<<<2048, 256, 0, stream>>>(qnb, knb, vbb, gbuf, bbuf, attnb, vadjb, kcdn, qgb, kdTb, egl);
  scan_kernel<<<dim3(64, 4), 256, 0, stream>>>(qgb, kcdn, attnb, kdTb, vadjb, egl, obuf);
  gate_kernel<<<131072, 64, 0, stream>>>(obuf, qkvzb, nw, gated);
  gemm_bt<false><<<dim3(32, 16), 256, 0, stream>>>(gated, WoT, out, 4096, 2048, 4096);
}

// Round 4
// 1013.605 us; speedup vs baseline: 1.2980x; 1.2980x over previous
//
#include <hip/hip_runtime.h>
#include <hip/hip_bf16.h>

// ---------------------------------------------------------------------------
// Qwen3.5 GatedDeltaNet forward, MI355X (gfx950)
// B=2 S=2048 HIDDEN=2048 HK=16 HV=32 DK=DV=128 KCONV=4 CHUNK=64
// R3->R4: chunk_kernel rewritten — per-thread register-column forward
// substitution (no Xs LDS, 3 barriers instead of 66, LDS 102KB->37KB);
// gate_kernel merged to 256-thread blocks.
// Workspace: 370,155,520 B with region aliasing (see kernel_launch).
// ---------------------------------------------------------------------------

typedef short bf16x8 __attribute__((ext_vector_type(8)));
typedef float f32x4  __attribute__((ext_vector_type(4)));

#define MFMA_BF16(a,b,c) __builtin_amdgcn_mfma_f32_16x16x32_bf16((a),(b),(c),0,0,0)
#define GLD16(g,l) __builtin_amdgcn_global_load_lds((const __attribute__((address_space(1))) void*)(g), (__attribute__((address_space(3))) void*)(l), 16, 0, 0)

__device__ __forceinline__ unsigned short f2bf(float x){
  union { float f; unsigned u; } v; v.f = x;
  return (unsigned short)((v.u + 0x7fffu + ((v.u >> 16) & 1u)) >> 16);
}
__device__ __forceinline__ float bf2f(unsigned short h){
  union { unsigned u; float f; } v; v.u = ((unsigned)h) << 16; return v.f;
}
__device__ __forceinline__ unsigned long long pack4bf(float a, float b, float c, float d){
  return (unsigned long long)f2bf(a) | ((unsigned long long)f2bf(b) << 16)
       | ((unsigned long long)f2bf(c) << 32) | ((unsigned long long)f2bf(d) << 48);
}

// ---------------------------------------------------------------------------
__global__ __launch_bounds__(256) void cast_bf16_kernel(
    const float* __restrict__ in, unsigned short* __restrict__ out, int n)
{
  int i = (blockIdx.x * 256 + threadIdx.x) * 4;
  if (i >= n) return;
  float4 v = *(const float4*)(in + i);
  *(unsigned long long*)(out + i) = pack4bf(v.x, v.y, v.z, v.w);
}

// transpose + cast: W[R][C] f32 -> WT[C][R] bf16
__global__ __launch_bounds__(256) void transpose_cast_kernel(
    const float* __restrict__ W, unsigned short* __restrict__ WT, int R, int C)
{
  __shared__ __attribute__((aligned(16))) float tile[32][33];
  int c0 = blockIdx.x * 32, r0 = blockIdx.y * 32;
  int tx = threadIdx.x & 31, ty = threadIdx.x >> 5;
  #pragma unroll
  for (int i = 0; i < 32; i += 8)
    tile[ty + i][tx] = W[(size_t)(r0 + ty + i) * C + c0 + tx];
  __syncthreads();
  #pragma unroll
  for (int i = 0; i < 32; i += 8)
    WT[(size_t)(c0 + ty + i) * R + r0 + tx] = f2bf(tile[tx][ty + i]);
}

// ---------------------------------------------------------------------------
// C[M][N] = A[M][K]bf16 * B[N][K]bf16^T  (128x128 tile, BK=32, XOR-swizzled LDS)
template<bool BF16OUT>
__global__ __launch_bounds__(256) void gemm_bt(
    const unsigned short* __restrict__ A,
    const unsigned short* __restrict__ B,
    void* __restrict__ Cv, int M, int N, int K)
{
  __shared__ __attribute__((aligned(16))) unsigned short Abuf[128 * 32];
  __shared__ __attribute__((aligned(16))) unsigned short Bbuf[128 * 32];
  const int tid  = threadIdx.x;
  const int wave = tid >> 6, lane = tid & 63;
  const int quad = lane >> 4, l16 = lane & 15;
  const int m0 = blockIdx.x * 128, n0 = blockIdx.y * 128;
  const int wm = (wave & 1) * 64, wn = (wave >> 1) * 64;

  f32x4 acc[4][4];
  #pragma unroll
  for (int a = 0; a < 4; ++a)
    #pragma unroll
    for (int b = 0; b < 4; ++b)
      #pragma unroll
      for (int r = 0; r < 4; ++r) acc[a][b][r] = 0.f;

  const int nkt = K >> 5;
  for (int kt = 0; kt < nkt; ++kt) {
    const int k0 = kt << 5;
    __syncthreads();
    #pragma unroll
    for (int c = 0; c < 2; ++c) {
      int p   = (wave * 2 + c) * 64 + lane;
      int m   = p >> 2;
      int gch = (p & 3) ^ ((m >> 2) & 3);
      GLD16(A + (size_t)(m0 + m) * K + k0 + gch * 8, Abuf + (wave * 2 + c) * 512);
      GLD16(B + (size_t)(n0 + m) * K + k0 + gch * 8, Bbuf + (wave * 2 + c) * 512);
    }
    __syncthreads();
    bf16x8 af[4], bfv[4];
    #pragma unroll
    for (int mt = 0; mt < 4; ++mt) {
      int m = wm + mt * 16 + l16;
      af[mt] = *(const bf16x8*)(Abuf + (m * 4 + (quad ^ ((m >> 2) & 3))) * 8);
    }
    #pragma unroll
    for (int nt = 0; nt < 4; ++nt) {
      int n = wn + nt * 16 + l16;
      bfv[nt] = *(const bf16x8*)(Bbuf + (n * 4 + (quad ^ ((n >> 2) & 3))) * 8);
    }
    #pragma unroll
    for (int mt = 0; mt < 4; ++mt)
      #pragma unroll
      for (int nt = 0; nt < 4; ++nt)
        acc[mt][nt] = MFMA_BF16(af[mt], bfv[nt], acc[mt][nt]);
  }
  #pragma unroll
  for (int mt = 0; mt < 4; ++mt) {
    #pragma unroll
    for (int nt = 0; nt < 4; ++nt) {
      int row = m0 + wm + mt * 16 + quad * 4;
      int col = n0 + wn + nt * 16 + l16;
      #pragma unroll
      for (int r = 0; r < 4; ++r) {
        if (BF16OUT)
          ((unsigned short*)Cv)[(size_t)(row + r) * N + col] = f2bf(acc[mt][nt][r]);
        else
          ((float*)Cv)[(size_t)(row + r) * N + col] = acc[mt][nt][r];
      }
    }
  }
}

// ---------------------------------------------------------------------------
// ba = H @ W_ba (fp32), beta = sigmoid(b), g = -exp(A_log)*softplus(a+dt_bias)
__global__ __launch_bounds__(256) void ba_kernel(
    const float* __restrict__ H, const float* __restrict__ Wba,
    const float* __restrict__ dtb, const float* __restrict__ Alog,
    float* __restrict__ bbuf, float* __restrict__ gbuf)
{
  int t = threadIdx.x;
  int col = t & 63, wv = t >> 6;
  int m0 = blockIdx.x * 16 + wv * 4;
  const float* h0 = H + (size_t)m0 * 2048;
  float a0 = 0.f, a1 = 0.f, a2 = 0.f, a3 = 0.f;
  for (int k = 0; k < 2048; ++k) {
    float w = Wba[k * 64 + col];
    a0 += h0[k]        * w;
    a1 += h0[2048 + k] * w;
    a2 += h0[4096 + k] * w;
    a3 += h0[6144 + k] * w;
  }
  float accv[4] = {a0, a1, a2, a3};
  #pragma unroll
  for (int r = 0; r < 4; ++r) {
    int m = m0 + r;
    int b = m >> 11, s = m & 2047;
    float acc = accv[r];
    if (col < 32) {
      bbuf[((size_t)(b * 32 + col)) * 2048 + s] = 1.f / (1.f + __expf(-acc));
    } else {
      int hh = col - 32;
      float x  = acc + dtb[hh];
      float sp = (x > 20.f) ? x : log1pf(__expf(x));
      gbuf[((size_t)(b * 32 + hh)) * 2048 + s] = -__expf(Alog[hh]) * sp;
    }
  }
}

// ---------------------------------------------------------------------------
// causal depthwise conv (K=4) + silu + (q,k) l2-norm (q also * DK^-0.5)
__global__ __launch_bounds__(128) void conv_kernel(
    const unsigned short* __restrict__ qkvz, const float* __restrict__ cw,
    unsigned short* __restrict__ qn, unsigned short* __restrict__ kn,
    unsigned short* __restrict__ vb)
{
  int s_base = blockIdx.x * 4;
  int head   = blockIdx.y;
  int d      = threadIdx.x;
  int col    = head * 128 + d;
  int s_loc  = s_base & 2047;

  float vin[7];
  #pragma unroll
  for (int t = 0; t < 7; ++t) {
    int sp = s_loc + t - 3;
    vin[t] = (sp >= 0) ? bf2f(qkvz[(size_t)(s_base + t - 3) * 12288 + col]) : 0.f;
  }
  float w0 = cw[col*4], w1 = cw[col*4+1], w2 = cw[col*4+2], w3 = cw[col*4+3];
  float y[4];
  #pragma unroll
  for (int u = 0; u < 4; ++u) {
    float acc = vin[u]*w0 + vin[u+1]*w1 + vin[u+2]*w2 + vin[u+3]*w3;
    y[u] = acc / (1.f + __expf(-acc));
  }
  if (head < 32) {
    __shared__ float red[2][4];
    int wv = threadIdx.x >> 6;
    #pragma unroll
    for (int u = 0; u < 4; ++u) {
      float ss = y[u] * y[u];
      #pragma unroll
      for (int off = 32; off; off >>= 1) ss += __shfl_down(ss, off);
      if ((threadIdx.x & 63) == 0) red[wv][u] = ss;
    }
    __syncthreads();
    #pragma unroll
    for (int u = 0; u < 4; ++u) {
      float r = rsqrtf(red[0][u] + red[1][u] + 1e-6f);
      if (head < 16)
        qn[((size_t)(s_base + u) * 16 + head) * 128 + d] = f2bf(y[u] * r * 0.08838834764831845f);
      else
        kn[((size_t)(s_base + u) * 16 + (head - 16)) * 128 + d] = f2bf(y[u] * r);
    }
  } else {
    #pragma unroll
    for (int u = 0; u < 4; ++u)
      vb[((size_t)(s_base + u) * 32 + (head - 32)) * 128 + d] = f2bf(y[u]);
  }
}

// ---------------------------------------------------------------------------
// per-chunk: A=(beta k)k^T * decay (strict lower), attn=q k^T * decay,
// register-column forward substitution (no barriers), outputs packed for scan.
__global__ __launch_bounds__(256) void chunk_kernel(
    const unsigned short* __restrict__ qnb, const unsigned short* __restrict__ knb,
    const unsigned short* __restrict__ vbb,
    const float* __restrict__ gbuf, const float* __restrict__ bbuf,
    unsigned short* __restrict__ attnb, unsigned short* __restrict__ vadjb,
    unsigned short* __restrict__ kcdn, unsigned short* __restrict__ qgb,
    unsigned short* __restrict__ kdT, float* __restrict__ egl)
{
  int cid = blockIdx.x;
  int n = cid & 31, h = (cid >> 5) & 31, b = cid >> 10;
  int h2 = h >> 1, s0 = n * 64;
  int gs0 = b * 2048 + s0;
  int tid = threadIdx.x, wave = tid >> 6, lane = tid & 63, quad = lane >> 4, l16 = lane & 15;

  __shared__ __attribute__((aligned(16))) unsigned short kS[64 * 136]; // bf16 k tile
  __shared__ __attribute__((aligned(16))) float As[64 * 68];           // fp32 A (strict lower)
  __shared__ float gcS[64], betaS[64];
  __shared__ float rsV[64], rsK[64], egq[64], egliS[64];

  if (tid < 64) {
    gcS[tid]   = gbuf[((size_t)(b * 32 + h)) * 2048 + s0 + tid];
    betaS[tid] = bbuf[((size_t)(b * 32 + h)) * 2048 + s0 + tid];
  }
  {                               // stage k tile -> LDS (bf16 copy)
    int i = tid >> 2, seg = tid & 3;
    const bf16x8* kp = (const bf16x8*)(knb + ((size_t)(gs0 + i) * 16 + h2) * 128 + seg * 32);
    bf16x8* kd_ = (bf16x8*)(kS + i * 136 + seg * 32);
    #pragma unroll
    for (int u = 0; u < 4; ++u) kd_[u] = kp[u];
  }
  __syncthreads();                // B1: gcS/betaS/kS staged
  if (tid == 0) {                 // inclusive cumsum of g
    float run = 0.f;
    for (int i = 0; i < 64; ++i) { run += gcS[i]; gcS[i] = run; }
  }
  __syncthreads();                // B2: cumsum done

  if (tid < 64) {                 // per-row scales (concurrent with phase 1)
    float gi = gcS[tid];
    rsV[tid]   = betaS[tid];
    rsK[tid]   = betaS[tid] * __expf(gi);
    egq[tid]   = __expf(gi);
    egliS[tid] = __expf(gcS[63] - gi);
    if (tid == 0) egl[cid] = __expf(gcS[63]);
  }

  // phase 1: A and attn via MFMA (wave w owns i-tile w)
  {
    int arow = wave * 16 + l16;
    float bscale = betaS[arow];
    const unsigned short* qpg = qnb + ((size_t)(gs0 + arow) * 16 + h2) * 128;
    bf16x8 kbf[4], qf[4];
    #pragma unroll
    for (int ks = 0; ks < 4; ++ks) {
      bf16x8 kfr = *(const bf16x8*)(kS + arow * 136 + ks * 32 + quad * 8);
      bf16x8 t;
      #pragma unroll
      for (int e = 0; e < 8; ++e)
        t[e] = (short)f2bf(bf2f((unsigned short)kfr[e]) * bscale);
      kbf[ks] = t;
      qf[ks] = *(const bf16x8*)(qpg + ks * 32 + quad * 8);
    }
    #pragma unroll
    for (int jt = 0; jt < 4; ++jt) {
      f32x4 accA, accQ;
      #pragma unroll
      for (int r = 0; r < 4; ++r) { accA[r] = 0.f; accQ[r] = 0.f; }
      #pragma unroll
      for (int ks = 0; ks < 4; ++ks) {
        bf16x8 bfr = *(const bf16x8*)(kS + (jt * 16 + l16) * 136 + ks * 32 + quad * 8);
        accA = MFMA_BF16(kbf[ks], bfr, accA);
        accQ = MFMA_BF16(qf[ks],  bfr, accQ);
      }
      #pragma unroll
      for (int r = 0; r < 4; ++r) {
        int i = wave * 16 + quad * 4 + r;
        int j = jt * 16 + l16;
        float e = __expf(gcS[i] - gcS[j]);
        As[i * 68 + j] = (j < i) ? (accA[r] * e) : 0.f;
        attnb[(size_t)cid * 4096 + i * 64 + j] = (j <= i) ? f2bf(accQ[r] * e) : (unsigned short)0;
      }
    }
  }
  __syncthreads();                // B3: As + rs arrays ready

  // phase 2+3: per-thread register column + blocked forward substitution.
  // thread c<128 owns v-column c; thread c>=128 owns k-column c-128.
  {
    int c = tid;
    float x[64];
    if (c < 128) {
      const unsigned short* vp = vbb + ((size_t)gs0 * 32 + h) * 128 + c;
      #pragma unroll
      for (int i = 0; i < 64; ++i)
        x[i] = bf2f(vp[(size_t)i * 4096]) * rsV[i];
    } else {
      int ck = c - 128;
      #pragma unroll
      for (int i = 0; i < 64; ++i)
        x[i] = bf2f(kS[i * 136 + ck]) * rsK[i];
    }
    // blocked forward substitution: As strict-lower (zeros on/above diag make
    // full 16-wide row updates safe).
    #pragma unroll
    for (int bi = 0; bi < 4; ++bi) {
      const int base = bi * 16;
      // serial in-block rows
      #pragma unroll
      for (int ii = 1; ii < 16; ++ii) {
        const int r = base + ii;
        const f32x4* ar = (const f32x4*)(As + r * 68 + base);
        float s = 0.f;
        #pragma unroll
        for (int g = 0; g < 4; ++g) {
          f32x4 a4 = ar[g];
          s += a4[0] * x[base + g*4] + a4[1] * x[base + g*4 + 1]
             + a4[2] * x[base + g*4 + 2] + a4[3] * x[base + g*4 + 3];
        }
        x[r] -= s;
      }
      // batch update of rows below this block
      #pragma unroll
      for (int r = base + 16; r < 64; ++r) {
        const f32x4* ar = (const f32x4*)(As + r * 68 + base);
        float s = 0.f;
        #pragma unroll
        for (int g = 0; g < 4; ++g) {
          f32x4 a4 = ar[g];
          s += a4[0] * x[base + g*4] + a4[1] * x[base + g*4 + 1]
             + a4[2] * x[base + g*4 + 2] + a4[3] * x[base + g*4 + 3];
        }
        x[r] -= s;
      }
    }
    // column store: vadj (c<128) / negated kcd (c>=128), coalesced 2B stores
    if (c < 128) {
      unsigned short* vo = vadjb + (size_t)cid * 8192 + c;
      #pragma unroll
      for (int i = 0; i < 64; ++i) vo[i * 128] = f2bf(x[i]);
    } else {
      unsigned short* ko = kcdn + (size_t)cid * 8192 + (c - 128);
      #pragma unroll
      for (int i = 0; i < 64; ++i) ko[i * 128] = f2bf(-x[i]);
    }
  }

  // phase 4: pack qg (q * e^gc) and kdT (k * e^(g_last - gc), transposed)
  {
    int i = tid >> 2, seg = tid & 3;
    float egli = egliS[i];
    float eqi  = egq[i];
    size_t base128 = (size_t)cid * 8192 + i * 128 + seg * 32;
    const unsigned short* qp = qnb + ((size_t)(gs0 + i) * 16 + h2) * 128 + seg * 32;
    #pragma unroll
    for (int u = 0; u < 32; u += 4) {
      *(unsigned long long*)(qgb + base128 + u) =
          pack4bf(bf2f(qp[u]) * eqi, bf2f(qp[u+1]) * eqi, bf2f(qp[u+2]) * eqi, bf2f(qp[u+3]) * eqi);
    }
    const unsigned short* kp = kS + i * 136 + seg * 32;
    unsigned short* kdo = kdT + (size_t)cid * 8192;
    #pragma unroll
    for (int u = 0; u < 32; ++u) {
      int d = seg * 32 + u;
      kdo[(size_t)d * 64 + i] = f2bf(bf2f(kp[u]) * egli);
    }
  }
}

// ---------------------------------------------------------------------------
// sequential scan over 32 chunks. grid (64 bh, 4 dv-slices of 32). MFMA throughout.
__global__ __launch_bounds__(256) void scan_kernel(
    const unsigned short* __restrict__ qgb, const unsigned short* __restrict__ kcdn,
    const unsigned short* __restrict__ attnb, const unsigned short* __restrict__ kdT,
    const unsigned short* __restrict__ vadjb, const float* __restrict__ egl,
    unsigned short* __restrict__ obuf)
{
  int bh = blockIdx.x, dv0 = blockIdx.y * 32;
  int tid = threadIdx.x, w = tid >> 6, lane = tid & 63, quad = lane >> 4, l16 = lane & 15;
  __shared__ __attribute__((aligned(16))) unsigned short stT[32 * 136];
  __shared__ __attribute__((aligned(16))) unsigned short vnT[32 * 72];

  for (int idx = tid; idx < 32 * 136; idx += 256) stT[idx] = 0;
  f32x4 st[2][2];
  #pragma unroll
  for (int a = 0; a < 2; ++a)
    #pragma unroll
    for (int bq = 0; bq < 2; ++bq)
      #pragma unroll
      for (int r = 0; r < 4; ++r) st[a][bq][r] = 0.f;
  __syncthreads();

  for (int n = 0; n < 32; ++n) {
    size_t cid = (size_t)bh * 32 + n;
    const unsigned short* qgc = qgb  + cid * 8192;
    const unsigned short* kcc = kcdn + cid * 8192;
    const unsigned short* atc = attnb + cid * 4096;
    const unsigned short* kdc = kdT  + cid * 8192;
    const unsigned short* vac = vadjb + cid * 8192;
    float a = egl[cid];

    bf16x8 sf[2][4];
    #pragma unroll
    for (int ni = 0; ni < 2; ++ni)
      #pragma unroll
      for (int ks = 0; ks < 4; ++ks)
        sf[ni][ks] = *(const bf16x8*)(stT + (ni * 16 + l16) * 136 + ks * 32 + quad * 8);

    // v_new = v_adj - kcd @ state  (kcd stored negated)
    f32x4 vacc[2];
    #pragma unroll
    for (int ni = 0; ni < 2; ++ni)
      #pragma unroll
      for (int r = 0; r < 4; ++r)
        vacc[ni][r] = bf2f(vac[(size_t)(w * 16 + quad * 4 + r) * 128 + dv0 + ni * 16 + l16]);
    bf16x8 kf[4];
    #pragma unroll
    for (int ks = 0; ks < 4; ++ks)
      kf[ks] = *(const bf16x8*)(kcc + (size_t)(w * 16 + l16) * 128 + ks * 32 + quad * 8);
    #pragma unroll
    for (int ni = 0; ni < 2; ++ni)
      #pragma unroll
      for (int ks = 0; ks < 4; ++ks)
        vacc[ni] = MFMA_BF16(kf[ks], sf[ni][ks], vacc[ni]);

    // o (part1) = (q e^gc) @ state
    f32x4 oacc[2];
    #pragma unroll
    for (int ni = 0; ni < 2; ++ni)
      #pragma unroll
      for (int r = 0; r < 4; ++r) oacc[ni][r] = 0.f;
    bf16x8 qf[4];
    #pragma unroll
    for (int ks = 0; ks < 4; ++ks)
      qf[ks] = *(const bf16x8*)(qgc + (size_t)(w * 16 + l16) * 128 + ks * 32 + quad * 8);
    #pragma unroll
    for (int ni = 0; ni < 2; ++ni)
      #pragma unroll
      for (int ks = 0; ks < 4; ++ks)
        oacc[ni] = MFMA_BF16(qf[ks], sf[ni][ks], oacc[ni]);

    // publish v_new^T
    #pragma unroll
    for (int ni = 0; ni < 2; ++ni)
      #pragma unroll
      for (int r = 0; r < 4; ++r)
        vnT[(ni * 16 + l16) * 72 + w * 16 + quad * 4 + r] = f2bf(vacc[ni][r]);
    __syncthreads();

    // o (part2) += attn @ v_new ; store o (bf16)
    bf16x8 af2[2], vf[2][2];
    #pragma unroll
    for (int k2 = 0; k2 < 2; ++k2)
      af2[k2] = *(const bf16x8*)(atc + (size_t)(w * 16 + l16) * 64 + k2 * 32 + quad * 8);
    #pragma unroll
    for (int ni = 0; ni < 2; ++ni)
      #pragma unroll
      for (int k2 = 0; k2 < 2; ++k2)
        vf[ni][k2] = *(const bf16x8*)(vnT + (ni * 16 + l16) * 72 + k2 * 32 + quad * 8);
    #pragma unroll
    for (int ni = 0; ni < 2; ++ni)
      #pragma unroll
      for (int k2 = 0; k2 < 2; ++k2)
        oacc[ni] = MFMA_BF16(af2[k2], vf[ni][k2], oacc[ni]);
    unsigned short* op = obuf + ((size_t)bh * 2048 + n * 64) * 128;
    #pragma unroll
    for (int ni = 0; ni < 2; ++ni)
      #pragma unroll
      for (int r = 0; r < 4; ++r)
        op[(size_t)(w * 16 + quad * 4 + r) * 128 + dv0 + ni * 16 + l16] = f2bf(oacc[ni][r]);

    // state = a*state + kdT @ v_new  (fp32 master in regs)
    #pragma unroll
    for (int mi = 0; mi < 2; ++mi) {
      int mg = (w * 2 + mi) * 16;
      bf16x8 kdf[2];
      #pragma unroll
      for (int k2 = 0; k2 < 2; ++k2)
        kdf[k2] = *(const bf16x8*)(kdc + (size_t)(mg + l16) * 64 + k2 * 32 + quad * 8);
      #pragma unroll
      for (int ni = 0; ni < 2; ++ni) {
        f32x4 acc_;
        #pragma unroll
        for (int r = 0; r < 4; ++r) acc_[r] = a * st[mi][ni][r];
        #pragma unroll
        for (int k2 = 0; k2 < 2; ++k2)
          acc_ = MFMA_BF16(kdf[k2], vf[ni][k2], acc_);
        st[mi][ni] = acc_;
      }
    }
    // publish state^T bf16 for next chunk
    #pragma unroll
    for (int mi = 0; mi < 2; ++mi)
      #pragma unroll
      for (int ni = 0; ni < 2; ++ni)
        #pragma unroll
        for (int r = 0; r < 4; ++r)
          stT[(ni * 16 + l16) * 136 + (w * 2 + mi) * 16 + quad * 4 + r] = f2bf(st[mi][ni][r]);
    __syncthreads();
  }
}

// ---------------------------------------------------------------------------
// gated RMSNorm: rmsnorm(o)*w*silu(z) -> gated bf16. 4 heads per 256-thr block.
__global__ __launch_bounds__(256) void gate_kernel(
    const unsigned short* __restrict__ obuf, const unsigned short* __restrict__ qkvz,
    const float* __restrict__ nw, unsigned short* __restrict__ gated)
{
  int id = blockIdx.x * 4 + (threadIdx.x >> 6);   // (b*2048+s)*32 + h
  int h = id & 31, bs = id >> 5;
  int b = bs >> 11, s = bs & 2047;
  int lane = threadIdx.x & 63;
  const unsigned short* op = obuf + (((size_t)(b * 32 + h)) * 2048 + s) * 128;
  const unsigned short* zp = qkvz + (size_t)bs * 12288 + 8192 + h * 128;
  float x0 = bf2f(op[lane]), x1 = bf2f(op[lane + 64]);
  float ss = x0 * x0 + x1 * x1;
  #pragma unroll
  for (int off = 32; off; off >>= 1) ss += __shfl_down(ss, off);
  ss = __shfl(ss, 0);
  float r = rsqrtf(ss * (1.f / 128.f) + 1e-6f);
  float z0 = bf2f(zp[lane]), z1 = bf2f(zp[lane + 64]);
  float g0 = z0 / (1.f + __expf(-z0)), g1 = z1 / (1.f + __expf(-z1));
  unsigned short* gp = gated + (size_t)bs * 4096 + h * 128;
  gp[lane]      = f2bf(x0 * r * nw[lane]      * g0);
  gp[lane + 64] = f2bf(x1 * r * nw[lane + 64] * g1);
}

// ---------------------------------------------------------------------------
extern "C" void kernel_launch(void* const* d_in, const int* in_sizes, int n_in,
                              void* d_out, int out_size, void* d_ws, size_t ws_size,
                              hipStream_t stream)
{
  const float* H     = (const float*)d_in[0];
  const float* Wqkvz = (const float*)d_in[1];
  const float* Wba   = (const float*)d_in[2];
  const float* cw    = (const float*)d_in[3];
  const float* dtb   = (const float*)d_in[4];
  const float* Alog  = (const float*)d_in[5];
  const float* nw    = (const float*)d_in[6];
  const float* Wout  = (const float*)d_in[7];
  float* out = (float*)d_out;

  // ---- workspace arena (370,155,520 B) with aliasing ----
  const size_t U1 = 0;                      //  67,108,864: Hbf+WqT -> qn+kn+vb
  const size_t U2 = U1 + 67108864;          // 100,663,296: qkvz bf16 (z until gate)
  const size_t U3 = U2 + 100663296;         //  16,777,216: WoT
  const size_t U4 = U3 + 16777216;          //   1,048,576: bbuf+gbuf
  const size_t U5 = U4 + 1048576;           // 151,003,136: chunk outputs -> gated
  const size_t U6 = U5 + 151003136;         //  33,554,432: obuf bf16
  const size_t NEED = U6 + 33554432;        // 370,155,520
  if (ws_size < NEED) return;               // graceful fail (diagnostic)

  char* base = (char*)d_ws;
  unsigned short* Hbf   = (unsigned short*)(base + U1);
  unsigned short* WqT   = (unsigned short*)(base + U1 + 16777216);
  unsigned short* qnb   = (unsigned short*)(base + U1);              // after GEMM1
  unsigned short* knb   = (unsigned short*)(base + U1 + 16777216);   // after GEMM1
  unsigned short* vbb   = (unsigned short*)(base + U1 + 33554432);   // after GEMM1
  unsigned short* qkvzb = (unsigned short*)(base + U2);
  unsigned short* WoT   = (unsigned short*)(base + U3);
  float*          bbuf  = (float*)(base + U4);
  float*          gbuf  = (float*)(base + U4 + 524288);
  unsigned short* attnb = (unsigned short*)(base + U5);
  unsigned short* vadjb = (unsigned short*)(base + U5 + 16777216);
  unsigned short* kcdn  = (unsigned short*)(base + U5 + 50331648);
  unsigned short* qgb   = (unsigned short*)(base + U5 + 83886080);
  unsigned short* kdTb  = (unsigned short*)(base + U5 + 117440512);
  float*          egl   = (float*)(base + U5 + 150994944);
  unsigned short* gated = (unsigned short*)(base + U5);              // after scan
  unsigned short* obuf  = (unsigned short*)(base + U6);

  cast_bf16_kernel<<<8192, 256, 0, stream>>>(H, Hbf, 4096 * 2048);
  transpose_cast_kernel<<<dim3(12288 / 32, 2048 / 32), 256, 0, stream>>>(Wqkvz, WqT, 2048, 12288);
  transpose_cast_kernel<<<dim3(2048 / 32, 4096 / 32), 256, 0, stream>>>(Wout, WoT, 4096, 2048);
  gemm_bt<true><<<dim3(32, 96), 256, 0, stream>>>(Hbf, WqT, qkvzb, 4096, 12288, 2048);
  ba_kernel<<<256, 256, 0, stream>>>(H, Wba, dtb, Alog, bbuf, gbuf);
  conv_kernel<<<dim3(1024, 64), 128, 0, stream>>>(qkvzb, cw, qnb, knb, vbb);
  chunk_kernel<<<2048, 256, 0, stream>>>(qnb, knb, vbb, gbuf, bbuf, attnb, vadjb, kcdn, qgb, kdTb, egl);
  scan_kernel<<<dim3(64, 4), 256, 0, stream>>>(qgb, kcdn, attnb, kdTb, vadjb, egl, obuf);
  gate_kernel<<<32768, 256, 0, stream>>>(obuf, qkvzb, nw, gated);
  gemm_bt<false><<<dim3(32, 16), 256, 0, stream>>>(gated, WoT, out, 4096, 2048, 4096);
}